// Round 17
// baseline (7265.483 us; speedup 1.0000x reference)
//
#include <hip/hip_runtime.h>
#include <hip/hip_fp16.h>

#define B_   256
#define T_   512
#define D_   200
#define H_   320
#define L_   3
#define G3_  960
#define BH_  (B_*H_)
#define BTH_ (B_*T_*H_)

#define GR_   8              // groups = XCDs
#define RPG_  32             // rows (batch) per group
#define CPB_  48             // output cols per block
#define NCG_  20             // col-groups per layer (960/48)
#define SPG_  60             // workers per group (3 layers * 20)
#define NP2_  24             // workers owning phase-2 tasks (96/4)
#define NBLK  512            // 2/CU fill -> ~64 blocks/XCD -> each group fills
#define NTHR  256
#define KIP0  224            // layer-0 input K padded to 32-multiple
#define WSTR  648            // LDS weight row stride in f16 elems

typedef _Float16 half8 __attribute__((ext_vector_type(8)));
typedef float    f32x4 __attribute__((ext_vector_type(4)));

// ---- ws layout (float units) ----
#define OFF_Z     0
#define SZ_Z      (L_*B_*G3_)
#define OFF_HN    (OFF_Z + SZ_Z)
#define SZ_HN     (L_*B_*H_)
#define OFF_STF   (OFF_HN + SZ_HN)
#define SZ_STF_F  ((L_*BH_)/2)
#define OFF_BAR   (OFF_STF + SZ_STF_F)
// per group: flagsA[60] @0 (spaced 32 words), flagsB[24] @FB_OFF; tickets after
#define FLAG_STR  32
#define FB_OFF    2048
#define GRP_STR   4096
#define TCK_OFF   (GR_*GRP_STR)
#define BAR_WORDS (GR_*GRP_STR + 256)

__device__ __forceinline__ float sigmoidf_(float v) {
    return 1.0f / (1.0f + __expf(-v));
}

__device__ __forceinline__ float wredsum(float v) {
#pragma unroll
    for (int m = 32; m > 0; m >>= 1) v += __shfl_xor(v, m, 64);
    return v;
}

__device__ __forceinline__ half8 h8zero() {
    half8 a;
#pragma unroll
    for (int j = 0; j < 8; ++j) a[j] = (_Float16)0.f;
    return a;
}

// L2-local (workgroup-scope) flag helpers
__device__ __forceinline__ void l2st(unsigned* p, unsigned v) {
    __hip_atomic_store(p, v, __ATOMIC_RELAXED, __HIP_MEMORY_SCOPE_WORKGROUP);
}
__device__ __forceinline__ unsigned l2ticket(unsigned* p) {
    return __hip_atomic_fetch_add(p, 1u, __ATOMIC_RELAXED, __HIP_MEMORY_SCOPE_WORKGROUP);
}

// -------- leaderless producer/consumer barriers (XCD-local, plain data) -----
__device__ __forceinline__ void bar_signal(unsigned* flags, int idx, int tid,
                                           unsigned token) {
    __syncthreads();
    if (tid == 0) l2st(&flags[idx*FLAG_STR], token);
}
__device__ __forceinline__ void bar_wait(unsigned* flags, int nflags, int tid,
                                         unsigned token) {
    if (tid < 64) {
        for (;;) {
            asm volatile("buffer_inv" ::: "memory");
            unsigned v = token;
            if (tid < nflags) v = ((volatile unsigned*)flags)[tid*FLAG_STR];
            if (__all((int)(v - token) >= 0)) break;
            __builtin_amdgcn_s_sleep(1);
        }
    }
    __syncthreads();
    asm volatile("buffer_inv" ::: "memory");
}

__device__ __forceinline__ void load_weights(int l, int colbase, int tid,
        const float* __restrict__ wih0, const float* __restrict__ wihr,
        const float* __restrict__ whh,  const float* __restrict__ rmean,
        const float* __restrict__ rvar,
        _Float16 (*w)[WSTR], float (*nrm)[KIP0])
{
    for (int e = tid; e < CPB_*WSTR; e += NTHR) ((_Float16*)w)[e] = (_Float16)0.f;
    if (l == 0) for (int e = tid; e < 2*KIP0; e += NTHR) ((float*)nrm)[e] = 0.f;
    __syncthreads();
    const int KI  = (l == 0) ? D_ : H_;
    const int KIP = (l == 0) ? KIP0 : H_;
    for (int e = tid; e < CPB_*KI; e += NTHR) {
        int c = e / KI, k = e - c*KI;
        float v = (l == 0) ? wih0[(size_t)(colbase + c)*D_ + k]
                           : wihr[((size_t)(l-1)*G3_ + colbase + c)*H_ + k];
        w[c][k] = (_Float16)v;
    }
    for (int e = tid; e < CPB_*H_; e += NTHR) {
        int c = e / H_, k = e - c*H_;
        w[c][KIP + k] = (_Float16)whh[((size_t)l*G3_ + colbase + c)*H_ + k];
    }
    if (l == 0) {
        for (int k = tid; k < D_; k += NTHR) {
            nrm[0][k] = rmean[k];
            nrm[1][k] = rsqrtf(rvar[k] + 1e-8f);
        }
    }
    __syncthreads();
}

// phase1: for L0, aI fragments come prefetched in registers (aIpre).
template<int KTI, bool L0>
__device__ __forceinline__ void phase1_work(int g, int l, int t, int colbase, int tid,
        const _Float16* __restrict__ stf,
        const float* __restrict__ bih, const float* __restrict__ bhh,
        float* __restrict__ zbuf, float* __restrict__ hnbuf,
        const _Float16 (*w)[WSTR], const half8* aIpre)
{
    const int wid  = tid >> 6;       // 0 or 1 (caller gates wid<2)
    const int lane = tid & 63;
    const int nr   = lane & 15;
    const int grp  = lane >> 4;
    const int mb   = g*RPG_ + wid*16;
    constexpr int KIP = KTI * 32;

    half8 aI[KTI];
    if (L0) {
#pragma unroll
        for (int kt = 0; kt < KTI; ++kt) aI[kt] = aIpre[kt];
    } else {
        const _Float16* srcI = &stf[(size_t)(l-1)*BH_ + (size_t)(mb + nr)*H_ + grp*8];
#pragma unroll
        for (int kt = 0; kt < KTI; ++kt) aI[kt] = *(const half8*)(srcI + kt*32);
    }
    half8 aH[10];
    {
        const _Float16* srcH = &stf[(size_t)l*BH_ + (size_t)(mb + nr)*H_ + grp*8];
#pragma unroll
        for (int kt = 0; kt < 10; ++kt) aH[kt] = *(const half8*)(srcH + kt*32);
    }

    f32x4 accI[3], accH[3];
#pragma unroll
    for (int nt = 0; nt < 3; ++nt) {
#pragma unroll
        for (int r = 0; r < 4; ++r) { accI[nt][r] = 0.f; accH[nt][r] = 0.f; }
    }

#pragma unroll
    for (int kt = 0; kt < KTI; ++kt) {
        const int k0 = kt*32 + grp*8;
#pragma unroll
        for (int nt = 0; nt < 3; ++nt) {
            half8 bf = *(const half8*)&w[nt*16 + nr][k0];
            accI[nt] = __builtin_amdgcn_mfma_f32_16x16x32_f16(aI[kt], bf, accI[nt], 0, 0, 0);
        }
    }
#pragma unroll
    for (int kt = 0; kt < 10; ++kt) {
        const int k0 = kt*32 + grp*8;
#pragma unroll
        for (int nt = 0; nt < 3; ++nt) {
            half8 bf = *(const half8*)&w[nt*16 + nr][KIP + k0];
            accH[nt] = __builtin_amdgcn_mfma_f32_16x16x32_f16(aH[kt], bf, accH[nt], 0, 0, 0);
        }
    }

    // ---- store pre-activations: plain write-through stores (local L2) ----
#pragma unroll
    for (int nt = 0; nt < 3; ++nt) {
        const int col = colbase + nt*16 + nr;
        const float bi = bih[l*G3_ + col];
        const float bh = bhh[l*G3_ + col];
        const bool ru = (colbase + nt*16) < 2*H_;
#pragma unroll
        for (int r = 0; r < 4; ++r) {
            const int m = mb + grp*4 + r;
            const size_t zi = ((size_t)l*B_ + m)*G3_ + col;
            if (ru) {
                zbuf[zi] = accI[nt][r] + accH[nt][r] + bi + bh;
            } else {
                zbuf[zi] = accI[nt][r] + bi;
                hnbuf[((size_t)l*B_ + m)*H_ + (col - 2*H_)] = accH[nt][r] + bh;
            }
        }
    }
}

// phase2 core: LN + gates + h update; writes stf (L2) only; returns hv in hv5.
__device__ __forceinline__ void phase2_core(int l2, int b2, int lane,
        const float* g0r, const float* c0r, const float* g1r, const float* c1r,
        const float* g2r, const float* c2r,
        float* hreg, float* hv5, _Float16* __restrict__ stf,
        const float* __restrict__ zbuf, const float* __restrict__ hnbuf)
{
    const float* zrow  = &zbuf[((size_t)l2*B_ + b2)*G3_];
    const float* hnrow = &hnbuf[((size_t)l2*B_ + b2)*H_];
    _Float16*    frow  = &stf[(size_t)l2*BH_ + (size_t)b2*H_];

    float zr[5], zu[5], zn[5], hn[5];
#pragma unroll
    for (int i = 0; i < 5; ++i) {
        const int j = lane + i*64;
        zr[i] = zrow[j];
        zu[i] = zrow[320 + j];
        zn[i] = zrow[640 + j];
        hn[i] = hnrow[j];
    }
    const float inv320 = 1.0f/320.0f;
    float s  = zr[0]+zr[1]+zr[2]+zr[3]+zr[4];
    float mu = wredsum(s) * inv320;
    float vs = 0.f;
#pragma unroll
    for (int i = 0; i < 5; ++i) { float d = zr[i]-mu; vs += d*d; }
    float inv = rsqrtf(wredsum(vs)*inv320 + 1e-5f);
    float r[5];
#pragma unroll
    for (int i = 0; i < 5; ++i)
        r[i] = sigmoidf_((zr[i]-mu)*inv * g0r[i] + c0r[i]);
    s  = zu[0]+zu[1]+zu[2]+zu[3]+zu[4];
    mu = wredsum(s) * inv320;
    vs = 0.f;
#pragma unroll
    for (int i = 0; i < 5; ++i) { float d = zu[i]-mu; vs += d*d; }
    inv = rsqrtf(wredsum(vs)*inv320 + 1e-5f);
    float u[5];
#pragma unroll
    for (int i = 0; i < 5; ++i)
        u[i] = sigmoidf_((zu[i]-mu)*inv * g1r[i] + c1r[i]);
    float z2[5];
#pragma unroll
    for (int i = 0; i < 5; ++i) z2[i] = zn[i] + r[i]*hn[i];
    s  = z2[0]+z2[1]+z2[2]+z2[3]+z2[4];
    mu = wredsum(s) * inv320;
    vs = 0.f;
#pragma unroll
    for (int i = 0; i < 5; ++i) { float d = z2[i]-mu; vs += d*d; }
    inv = rsqrtf(wredsum(vs)*inv320 + 1e-5f);
#pragma unroll
    for (int i = 0; i < 5; ++i) {
        const int j = lane + i*64;
        float nv = tanhf((z2[i]-mu)*inv * g2r[i] + c2r[i]);
        float hv = (1.0f - u[i])*nv + u[i]*hreg[i];
        hreg[i] = hv;
        hv5[i]  = hv;
        // f16 state: pair adjacent lanes -> one plain 4B store per even lane
        unsigned hb = (unsigned)__builtin_bit_cast(unsigned short, (_Float16)hv);
        unsigned ob = (unsigned)__shfl_xor((int)hb, 1, 64);
        if ((lane & 1) == 0)
            ((unsigned*)frow)[j >> 1] = (hb & 0xffffu) | (ob << 16);
    }
}

// ---- init: zero barrier+ticket area, init f16 state from h0 ----
__global__ void k_init(const float* __restrict__ h0, float* __restrict__ ws) {
    _Float16*  stf = (_Float16*)(ws + OFF_STF);
    unsigned*  bar = (unsigned*)(ws + OFF_BAR);
    int gt = blockIdx.x*blockDim.x + threadIdx.x;
    for (int i = gt; i < BAR_WORDS; i += gridDim.x*blockDim.x) bar[i] = 0u;
    for (int i = gt; i < L_*BH_; i += gridDim.x*blockDim.x)
        stf[i] = (_Float16)h0[i];
}

// ================= persistent kernel (plain launch, XCD-local groups) =======
__launch_bounds__(NTHR, 2)
__global__ void gru_pers_kernel(const float* __restrict__ x,
                                const float* __restrict__ h0,
                                const float* __restrict__ rmean,
                                const float* __restrict__ rvar,
                                const float* __restrict__ wih0,
                                const float* __restrict__ wihr,
                                const float* __restrict__ whh,
                                const float* __restrict__ bih,
                                const float* __restrict__ bhh,
                                const float* __restrict__ lng,
                                const float* __restrict__ lnb,
                                float* __restrict__ out,
                                float* __restrict__ ws)
{
    float*     zbuf  = ws + OFF_Z;
    float*     hnbuf = ws + OFF_HN;
    _Float16*  stf   = (_Float16*)(ws + OFF_STF);
    unsigned*  bar   = (unsigned*)(ws + OFF_BAR);

    const int tid = threadIdx.x;

    // ---- ticket-based XCD-local group formation ----
    unsigned myxcd;
    asm volatile("s_getreg_b32 %0, hwreg(HW_REG_XCC_ID)" : "=s"(myxcd));
    myxcd &= 7u;
    __shared__ unsigned sh_slot;
    if (tid == 0) sh_slot = l2ticket(&bar[TCK_OFF + myxcd*32]);
    __syncthreads();
    const unsigned slot = sh_slot;
    if (slot >= (unsigned)SPG_) return;

    const int g   = (int)myxcd;
    const int idx = (int)slot;
    const int l   = idx / NCG_;
    const int cgp = idx - l*NCG_;
    const int colbase = cgp * CPB_;
    const bool p2blk = (idx < NP2_);

    unsigned* flagsA = bar + g*GRP_STR;
    unsigned* flagsB = bar + g*GRP_STR + FB_OFF;

    __shared__ _Float16 w_lds[CPB_][WSTR];     // 62208 B
    __shared__ float    nrm_lds[2][KIP0];      //  1792 B

    load_weights(l, colbase, tid, wih0, wihr, whh, rmean, rvar, w_lds, nrm_lds);

    const int wid  = tid >> 6;
    const int lane = tid & 63;
    const int wv   = idx*4 + wid;
    const int nr   = lane & 15;
    const int grp  = lane >> 4;

    // phase-2 task constants + hidden state + LN params in registers
    const bool p2act = p2blk && (wv < L_*RPG_);
    const int  l2 = wv >> 5, row = wv & 31, b2 = g*RPG_ + row;
    float hreg[5] = {0.f, 0.f, 0.f, 0.f, 0.f};
    float g0r[5], c0r[5], g1r[5], c1r[5], g2r[5], c2r[5];
    if (p2act) {
#pragma unroll
        for (int i = 0; i < 5; ++i) {
            const int j = lane + i*64;
            hreg[i] = h0[(size_t)l2*BH_ + (size_t)b2*H_ + j];
            g0r[i] = lng[(l2*3+0)*H_ + j];  c0r[i] = lnb[(l2*3+0)*H_ + j];
            g1r[i] = lng[(l2*3+1)*H_ + j];  c1r[i] = lnb[(l2*3+1)*H_ + j];
            g2r[i] = lng[(l2*3+2)*H_ + j];  c2r[i] = lnb[(l2*3+2)*H_ + j];
        }
    }

    // x prefetch registers (layer-0 blocks, waves 0-1 only)
    half8 aIx[7];
    const bool xload = (l == 0) && (wid < 2);
    const int  mbx   = g*RPG_ + wid*16;
    auto prefetch_x = [&](int t) {
        if (!xload || t >= T_) return;
#pragma unroll
        for (int kt = 0; kt < 7; ++kt) {
            if (kt == 6 && grp > 0) { aIx[kt] = h8zero(); continue; }
            const int k0 = kt*32 + grp*8;
            const float* xr = &x[((size_t)(mbx + nr)*T_ + t)*D_ + k0];
            float xv[8];
            *(float4*)&xv[0] = *(const float4*)xr;
            *(float4*)&xv[4] = *(const float4*)(xr + 4);
#pragma unroll
            for (int j = 0; j < 8; ++j) {
                float nv = (xv[j] - nrm_lds[0][k0+j]) * nrm_lds[1][k0+j];
                aIx[kt][j] = (_Float16)fminf(fmaxf(nv, -10.f), 10.f);
            }
        }
    };
    prefetch_x(0);

    for (int tau = 0; tau < T_ + L_ - 1; ++tau) {
        const unsigned tok = (unsigned)(tau + 1);
        const int t = tau - l;
        if (t >= 0 && t < T_ && wid < 2) {
            if (l == 0) phase1_work<7,  true >(g, l, t, colbase, tid, stf, bih, bhh,
                                               zbuf, hnbuf, w_lds, aIx);
            else        phase1_work<10, false>(g, l, t, colbase, tid, stf, bih, bhh,
                                               zbuf, hnbuf, w_lds, nullptr);
        }
        bar_signal(flagsA, idx, tid, tok);          // z of this block in L2
        prefetch_x(t + 1);                          // overlaps A-wait poll
        const int t2 = tau - l2;
        const bool act = p2act && t2 >= 0 && t2 < T_;
        float hv5[5];
        if (p2blk) {
            bar_wait(flagsA, SPG_, tid, tok);       // all 60 z-producers done
            if (act)
                phase2_core(l2, b2, lane, g0r, c0r, g1r, c1r, g2r, c2r,
                            hreg, hv5, stf, zbuf, hnbuf);
            bar_signal(flagsB, idx, tid, tok);      // stf in L2 (drained by sync)
            if (act) {                              // HBM out stores AFTER signal:
#pragma unroll                                      // drain overlaps B-wait poll
                for (int i = 0; i < 5; ++i) {
                    const int j = lane + i*64;
                    if (l2 == 2)    out[((size_t)b2*T_ + t2)*H_ + j] = hv5[i];
                    if (t2 == T_-1) out[(size_t)BTH_ + ((size_t)l2*B_ + b2)*H_ + j] = hv5[i];
                }
            }
        }
        bar_wait(flagsB, NP2_, tid, tok);           // all 24 h-producers done
    }
}

extern "C" void kernel_launch(void* const* d_in, const int* in_sizes, int n_in,
                              void* d_out, int out_size, void* d_ws, size_t ws_size,
                              hipStream_t stream) {
    (void)in_sizes; (void)n_in; (void)out_size; (void)ws_size;
    const float* x     = (const float*)d_in[0];
    const float* h0    = (const float*)d_in[1];
    const float* rmean = (const float*)d_in[2];
    const float* rvar  = (const float*)d_in[3];
    const float* wih0  = (const float*)d_in[4];
    const float* wihr  = (const float*)d_in[5];
    const float* whh   = (const float*)d_in[6];
    const float* bih   = (const float*)d_in[7];
    const float* bhh   = (const float*)d_in[8];
    const float* lng   = (const float*)d_in[9];
    const float* lnb   = (const float*)d_in[10];
    float* out = (float*)d_out;
    float* ws  = (float*)d_ws;

    // Plain launches only (coop rejected in r9/r10); no runtime queries.
    k_init<<<dim3(240), dim3(NTHR), 0, stream>>>(h0, ws);
    gru_pers_kernel<<<dim3(NBLK), dim3(NTHR), 0, stream>>>(
        x, h0, rmean, rvar, wih0, wihr, whh, bih, bhh, lng, lnb, out, ws);
}

// Round 18
// 5191.322 us; speedup vs baseline: 1.3995x; 1.3995x over previous
//
#include <hip/hip_runtime.h>
#include <hip/hip_fp16.h>

#define B_   256
#define T_   512
#define D_   200
#define H_   320
#define L_   3
#define G3_  960
#define BH_  (B_*H_)
#define BTH_ (B_*T_*H_)

#define GR_   8              // groups = XCDs
#define RPG_  32             // rows (batch) per group
#define CPB_  48             // output cols per block
#define NCG_  20             // col-groups per layer (960/48)
#define SPG_  60             // workers per group (3 layers * 20)
#define NP2_  24             // workers owning phase-2 tasks (96/4)
#define NBLK  512            // 2/CU fill -> ~64 blocks/XCD -> each group fills
#define NTHR  256
#define KIP0  224            // layer-0 input K padded to 32-multiple
#define WSTR  648            // LDS weight row stride in f16 elems

typedef _Float16 half8 __attribute__((ext_vector_type(8)));
typedef float    f32x4 __attribute__((ext_vector_type(4)));

// ---- ws layout (float units) ----
#define OFF_Z     0
#define SZ_Z      (L_*B_*G3_)
#define OFF_HN    (OFF_Z + SZ_Z)
#define SZ_HN     (L_*B_*H_)
#define OFF_STF   (OFF_HN + SZ_HN)
#define SZ_STF_F  ((L_*BH_)/2)
#define OFF_BAR   (OFF_STF + SZ_STF_F)
// per group: flagsA[60] @0 (spaced 32 words), flagsB[24] @FB_OFF; tickets after
#define FLAG_STR  32
#define FB_OFF    2048
#define GRP_STR   4096
#define TCK_OFF   (GR_*GRP_STR)
#define BAR_WORDS (GR_*GRP_STR + 256)

__device__ __forceinline__ float sigmoidf_(float v) {
    return 1.0f / (1.0f + __expf(-v));
}

__device__ __forceinline__ float wredsum(float v) {
#pragma unroll
    for (int m = 32; m > 0; m >>= 1) v += __shfl_xor(v, m, 64);
    return v;
}

__device__ __forceinline__ half8 h8zero() {
    half8 a;
#pragma unroll
    for (int j = 0; j < 8; ++j) a[j] = (_Float16)0.f;
    return a;
}

// L2-local (workgroup-scope) flag helpers: same-XCD blocks share the L2, so
// these never touch the far coherence point.
__device__ __forceinline__ void l2st(unsigned* p, unsigned v) {
    __hip_atomic_store(p, v, __ATOMIC_RELAXED, __HIP_MEMORY_SCOPE_WORKGROUP);
}
__device__ __forceinline__ unsigned l2ticket(unsigned* p) {
    return __hip_atomic_fetch_add(p, 1u, __ATOMIC_RELAXED, __HIP_MEMORY_SCOPE_WORKGROUP);
}

// -------- leaderless producer/consumer barriers (XCD-local, plain data) -----
// signal: __syncthreads drains vmcnt (write-through stores now in local L2),
// then one flag store. wait: wave-0 polls producer flags with per-iteration
// vL1 invalidate (buffer_inv = CU-local, no fabric traffic) + volatile loads;
// closing buffer_inv makes every wave's subsequent plain loads L2-fresh.
// Busy-spin (no s_sleep): detection quantum = one L2 round trip (r17 change).
__device__ __forceinline__ void bar_signal(unsigned* flags, int idx, int tid,
                                           unsigned token) {
    __syncthreads();
    if (tid == 0) l2st(&flags[idx*FLAG_STR], token);
}
__device__ __forceinline__ void bar_wait(unsigned* flags, int nflags, int tid,
                                         unsigned token) {
    if (tid < 64) {
        for (;;) {
            asm volatile("buffer_inv" ::: "memory");
            unsigned v = token;
            if (tid < nflags) v = ((volatile unsigned*)flags)[tid*FLAG_STR];
            if (__all((int)(v - token) >= 0)) break;
        }
    }
    __syncthreads();
    asm volatile("buffer_inv" ::: "memory");
}

__device__ __forceinline__ void load_weights(int l, int colbase, int tid,
        const float* __restrict__ wih0, const float* __restrict__ wihr,
        const float* __restrict__ whh,  const float* __restrict__ rmean,
        const float* __restrict__ rvar,
        _Float16 (*w)[WSTR], float (*nrm)[KIP0])
{
    for (int e = tid; e < CPB_*WSTR; e += NTHR) ((_Float16*)w)[e] = (_Float16)0.f;
    if (l == 0) for (int e = tid; e < 2*KIP0; e += NTHR) ((float*)nrm)[e] = 0.f;
    __syncthreads();
    const int KI  = (l == 0) ? D_ : H_;
    const int KIP = (l == 0) ? KIP0 : H_;
    for (int e = tid; e < CPB_*KI; e += NTHR) {
        int c = e / KI, k = e - c*KI;
        float v = (l == 0) ? wih0[(size_t)(colbase + c)*D_ + k]
                           : wihr[((size_t)(l-1)*G3_ + colbase + c)*H_ + k];
        w[c][k] = (_Float16)v;
    }
    for (int e = tid; e < CPB_*H_; e += NTHR) {
        int c = e / H_, k = e - c*H_;
        w[c][KIP + k] = (_Float16)whh[((size_t)l*G3_ + colbase + c)*H_ + k];
    }
    if (l == 0) {
        for (int k = tid; k < D_; k += NTHR) {
            nrm[0][k] = rmean[k];
            nrm[1][k] = rsqrtf(rvar[k] + 1e-8f);
        }
    }
    __syncthreads();
}

template<int KTI, bool L0>
__device__ __forceinline__ void phase1_work(int g, int l, int t, int colbase, int tid,
        const float* __restrict__ x, const _Float16* __restrict__ stf,
        const float* __restrict__ bih, const float* __restrict__ bhh,
        float* __restrict__ zbuf, float* __restrict__ hnbuf,
        const _Float16 (*w)[WSTR], const float (*nrm)[KIP0])
{
    const int wid  = tid >> 6;       // 0 or 1 (caller gates wid<2)
    const int lane = tid & 63;
    const int nr   = lane & 15;
    const int grp  = lane >> 4;
    const int mb   = g*RPG_ + wid*16;
    constexpr int KIP = KTI * 32;

    // plain cached loads (fresh: buffer_inv ran at barrier exit; data in local L2)
    half8 aI[KTI];
    if (L0) {
#pragma unroll
        for (int kt = 0; kt < KTI; ++kt) {
            if (kt == KTI-1 && grp > 0) { aI[kt] = h8zero(); continue; }
            const int k0 = kt*32 + grp*8;
            const float* xr = &x[((size_t)(mb + nr)*T_ + t)*D_ + k0];
            float xv[8];
            *(float4*)&xv[0] = *(const float4*)xr;
            *(float4*)&xv[4] = *(const float4*)(xr + 4);
#pragma unroll
            for (int j = 0; j < 8; ++j) {
                float nv = (xv[j] - nrm[0][k0+j]) * nrm[1][k0+j];
                aI[kt][j] = (_Float16)fminf(fmaxf(nv, -10.f), 10.f);
            }
        }
    } else {
        const _Float16* srcI = &stf[(size_t)(l-1)*BH_ + (size_t)(mb + nr)*H_ + grp*8];
#pragma unroll
        for (int kt = 0; kt < KTI; ++kt) aI[kt] = *(const half8*)(srcI + kt*32);
    }
    half8 aH[10];
    {
        const _Float16* srcH = &stf[(size_t)l*BH_ + (size_t)(mb + nr)*H_ + grp*8];
#pragma unroll
        for (int kt = 0; kt < 10; ++kt) aH[kt] = *(const half8*)(srcH + kt*32);
    }

    f32x4 accI[3], accH[3];
#pragma unroll
    for (int nt = 0; nt < 3; ++nt) {
#pragma unroll
        for (int r = 0; r < 4; ++r) { accI[nt][r] = 0.f; accH[nt][r] = 0.f; }
    }

#pragma unroll
    for (int kt = 0; kt < KTI; ++kt) {
        const int k0 = kt*32 + grp*8;
#pragma unroll
        for (int nt = 0; nt < 3; ++nt) {
            half8 bf = *(const half8*)&w[nt*16 + nr][k0];
            accI[nt] = __builtin_amdgcn_mfma_f32_16x16x32_f16(aI[kt], bf, accI[nt], 0, 0, 0);
        }
    }
#pragma unroll
    for (int kt = 0; kt < 10; ++kt) {
        const int k0 = kt*32 + grp*8;
#pragma unroll
        for (int nt = 0; nt < 3; ++nt) {
            half8 bf = *(const half8*)&w[nt*16 + nr][KIP + k0];
            accH[nt] = __builtin_amdgcn_mfma_f32_16x16x32_f16(aH[kt], bf, accH[nt], 0, 0, 0);
        }
    }

    // ---- store pre-activations: plain write-through stores (land in local L2)
#pragma unroll
    for (int nt = 0; nt < 3; ++nt) {
        const int col = colbase + nt*16 + nr;
        const float bi = bih[l*G3_ + col];
        const float bh = bhh[l*G3_ + col];
        const bool ru = (colbase + nt*16) < 2*H_;
#pragma unroll
        for (int r = 0; r < 4; ++r) {
            const int m = mb + grp*4 + r;
            const size_t zi = ((size_t)l*B_ + m)*G3_ + col;
            if (ru) {
                zbuf[zi] = accI[nt][r] + accH[nt][r] + bi + bh;
            } else {
                zbuf[zi] = accI[nt][r] + bi;
                hnbuf[((size_t)l*B_ + m)*H_ + (col - 2*H_)] = accH[nt][r] + bh;
            }
        }
    }
}

__device__ __forceinline__ void phase1_dispatch(int g, int l, int t, int colbase, int tid,
        const float* x, const _Float16* stf, const float* bih, const float* bhh,
        float* zbuf, float* hnbuf, const _Float16 (*w)[WSTR], const float (*nrm)[KIP0])
{
    if ((tid >> 6) >= 2) return;   // 2 waves of 16 rows cover RPG_=32
    if (l == 0) phase1_work<7,  true >(g, l, t, colbase, tid, x, stf, bih, bhh, zbuf, hnbuf, w, nrm);
    else        phase1_work<10, false>(g, l, t, colbase, tid, x, stf, bih, bhh, zbuf, hnbuf, w, nrm);
}

__device__ __forceinline__ void phase2_work(int g, int tau, int wv, int lane,
        const float* __restrict__ lng, const float* __restrict__ lnb,
        float* hreg, _Float16* __restrict__ stf,
        const float* __restrict__ zbuf, const float* __restrict__ hnbuf,
        float* __restrict__ out)
{
    if (wv >= L_*RPG_) return;            // 96 tasks per group
    const int l2  = wv >> 5;
    const int row = wv & 31;
    const int b2  = g*RPG_ + row;
    const int t2  = tau - l2;
    if (t2 < 0 || t2 >= T_) return;

    const float* zrow  = &zbuf[((size_t)l2*B_ + b2)*G3_];
    const float* hnrow = &hnbuf[((size_t)l2*B_ + b2)*H_];
    _Float16*    frow  = &stf[(size_t)l2*BH_ + (size_t)b2*H_];

    float zr[5], zu[5], zn[5], hn[5];
#pragma unroll
    for (int i = 0; i < 5; ++i) {
        const int j = lane + i*64;
        zr[i] = zrow[j];
        zu[i] = zrow[320 + j];
        zn[i] = zrow[640 + j];
        hn[i] = hnrow[j];
    }
    const float inv320 = 1.0f/320.0f;
    float s  = zr[0]+zr[1]+zr[2]+zr[3]+zr[4];
    float mu = wredsum(s) * inv320;
    float vs = 0.f;
#pragma unroll
    for (int i = 0; i < 5; ++i) { float d = zr[i]-mu; vs += d*d; }
    float inv = rsqrtf(wredsum(vs)*inv320 + 1e-5f);
    float r[5];
#pragma unroll
    for (int i = 0; i < 5; ++i) {
        const int j = lane + i*64;
        r[i] = sigmoidf_((zr[i]-mu)*inv * lng[(l2*3+0)*H_ + j] + lnb[(l2*3+0)*H_ + j]);
    }
    s  = zu[0]+zu[1]+zu[2]+zu[3]+zu[4];
    mu = wredsum(s) * inv320;
    vs = 0.f;
#pragma unroll
    for (int i = 0; i < 5; ++i) { float d = zu[i]-mu; vs += d*d; }
    inv = rsqrtf(wredsum(vs)*inv320 + 1e-5f);
    float u[5];
#pragma unroll
    for (int i = 0; i < 5; ++i) {
        const int j = lane + i*64;
        u[i] = sigmoidf_((zu[i]-mu)*inv * lng[(l2*3+1)*H_ + j] + lnb[(l2*3+1)*H_ + j]);
    }
    float z2[5];
#pragma unroll
    for (int i = 0; i < 5; ++i) z2[i] = zn[i] + r[i]*hn[i];
    s  = z2[0]+z2[1]+z2[2]+z2[3]+z2[4];
    mu = wredsum(s) * inv320;
    vs = 0.f;
#pragma unroll
    for (int i = 0; i < 5; ++i) { float d = z2[i]-mu; vs += d*d; }
    inv = rsqrtf(wredsum(vs)*inv320 + 1e-5f);
#pragma unroll
    for (int i = 0; i < 5; ++i) {
        const int j = lane + i*64;
        float nv = tanhf((z2[i]-mu)*inv * lng[(l2*3+2)*H_ + j] + lnb[(l2*3+2)*H_ + j]);
        float hv = (1.0f - u[i])*nv + u[i]*hreg[i];
        hreg[i] = hv;
        // f16 state: pair adjacent lanes -> one plain 4B store per even lane
        unsigned hb = (unsigned)__builtin_bit_cast(unsigned short, (_Float16)hv);
        unsigned ob = (unsigned)__shfl_xor((int)hb, 1, 64);
        if ((lane & 1) == 0)
            ((unsigned*)frow)[j >> 1] = (hb & 0xffffu) | (ob << 16);
        if (l2 == 2)    out[((size_t)b2*T_ + t2)*H_ + j] = hv;
        if (t2 == T_-1) out[(size_t)BTH_ + ((size_t)l2*B_ + b2)*H_ + j] = hv;
    }
}

// ---- init: zero barrier+ticket area, init f16 state from h0 ----
__global__ void k_init(const float* __restrict__ h0, float* __restrict__ ws) {
    _Float16*  stf = (_Float16*)(ws + OFF_STF);
    unsigned*  bar = (unsigned*)(ws + OFF_BAR);
    int gt = blockIdx.x*blockDim.x + threadIdx.x;
    for (int i = gt; i < BAR_WORDS; i += gridDim.x*blockDim.x) bar[i] = 0u;
    for (int i = gt; i < L_*BH_; i += gridDim.x*blockDim.x)
        stf[i] = (_Float16)h0[i];
}

// ================= persistent kernel (plain launch, XCD-local groups) =======
// Each block reads its physical XCC_ID and takes a ticket from its XCD's
// counter: slot<60 -> worker (group = XCD, idx = slot); slot>=60 -> exit.
// All group traffic (z, hn, stf, flags) stays in the XCD's L2: plain
// write-through stores + buffer_inv(vL1) on consume. Late-scheduled blocks
// self-heal: members block on monotonic tokens until the worker joins.
__launch_bounds__(NTHR, 2)
__global__ void gru_pers_kernel(const float* __restrict__ x,
                                const float* __restrict__ h0,
                                const float* __restrict__ rmean,
                                const float* __restrict__ rvar,
                                const float* __restrict__ wih0,
                                const float* __restrict__ wihr,
                                const float* __restrict__ whh,
                                const float* __restrict__ bih,
                                const float* __restrict__ bhh,
                                const float* __restrict__ lng,
                                const float* __restrict__ lnb,
                                float* __restrict__ out,
                                float* __restrict__ ws)
{
    float*     zbuf  = ws + OFF_Z;
    float*     hnbuf = ws + OFF_HN;
    _Float16*  stf   = (_Float16*)(ws + OFF_STF);
    unsigned*  bar   = (unsigned*)(ws + OFF_BAR);

    const int tid = threadIdx.x;

    // ---- ticket-based XCD-local group formation ----
    unsigned myxcd;
    asm volatile("s_getreg_b32 %0, hwreg(HW_REG_XCC_ID)" : "=s"(myxcd));
    myxcd &= 7u;
    __shared__ unsigned sh_slot;
    if (tid == 0) sh_slot = l2ticket(&bar[TCK_OFF + myxcd*32]);
    __syncthreads();
    const unsigned slot = sh_slot;
    if (slot >= (unsigned)SPG_) return;      // surplus block: free the CU slot

    const int g   = (int)myxcd;
    const int idx = (int)slot;
    const int l   = idx / NCG_;
    const int cgp = idx - l*NCG_;
    const int colbase = cgp * CPB_;
    const bool p2blk = (idx < NP2_);

    unsigned* flagsA = bar + g*GRP_STR;
    unsigned* flagsB = bar + g*GRP_STR + FB_OFF;

    __shared__ _Float16 w_lds[CPB_][WSTR];     // 62208 B
    __shared__ float    nrm_lds[2][KIP0];      //  1792 B

    load_weights(l, colbase, tid, wih0, wihr, whh, rmean, rvar, w_lds, nrm_lds);

    const int wid  = tid >> 6;
    const int lane = tid & 63;
    const int wv   = idx*4 + wid;

    float hreg[5] = {0.f, 0.f, 0.f, 0.f, 0.f};
    if (wv < L_*RPG_) {
        const int l2 = wv >> 5, row = wv & 31, b2 = g*RPG_ + row;
#pragma unroll
        for (int i = 0; i < 5; ++i)
            hreg[i] = h0[(size_t)l2*BH_ + (size_t)b2*H_ + lane + i*64];
    }

    for (int tau = 0; tau < T_ + L_ - 1; ++tau) {
        const unsigned tok = (unsigned)(tau + 1);
        const int t = tau - l;
        if (t >= 0 && t < T_)
            phase1_dispatch(g, l, t, colbase, tid, x, stf, bih, bhh,
                            zbuf, hnbuf, w_lds, nrm_lds);
        bar_signal(flagsA, idx, tid, tok);          // z of this block in L2
        if (p2blk) {
            bar_wait(flagsA, SPG_, tid, tok);       // all 60 z-producers done
            phase2_work(g, tau, wv, lane, lng, lnb, hreg, stf, zbuf, hnbuf, out);
            bar_signal(flagsB, idx, tid, tok);      // h of this block in L2
        }
        bar_wait(flagsB, NP2_, tid, tok);           // all 24 h-producers done
    }
}

extern "C" void kernel_launch(void* const* d_in, const int* in_sizes, int n_in,
                              void* d_out, int out_size, void* d_ws, size_t ws_size,
                              hipStream_t stream) {
    (void)in_sizes; (void)n_in; (void)out_size; (void)ws_size;
    const float* x     = (const float*)d_in[0];
    const float* h0    = (const float*)d_in[1];
    const float* rmean = (const float*)d_in[2];
    const float* rvar  = (const float*)d_in[3];
    const float* wih0  = (const float*)d_in[4];
    const float* wihr  = (const float*)d_in[5];
    const float* whh   = (const float*)d_in[6];
    const float* bih   = (const float*)d_in[7];
    const float* bhh   = (const float*)d_in[8];
    const float* lng   = (const float*)d_in[9];
    const float* lnb   = (const float*)d_in[10];
    float* out = (float*)d_out;
    float* ws  = (float*)d_ws;

    // Plain launches only (coop rejected in r9/r10); no runtime queries.
    k_init<<<dim3(240), dim3(NTHR), 0, stream>>>(h0, ws);
    gru_pers_kernel<<<dim3(NBLK), dim3(NTHR), 0, stream>>>(
        x, h0, rmean, rvar, wih0, wihr, whh, bih, bhh, lng, lnb, out, ws);
}